// Round 5
// baseline (346.702 us; speedup 1.0000x reference)
//
#include <hip/hip_runtime.h>

// MLP depends only on X[b] (1000 distinct values) -> params table once over
// embedding rows, gather in the scan. Scan = EXACT two-pass checkpoint
// scheme: scan_a (1 thread/row) runs the clipped recurrence latent-only and
// stores 8 checkpoint latents + 8x25-bit y masks per row; scan_b (8
// threads/row, full occupancy) re-emits each 25-step segment bit-identically
// from its checkpoint. No Mobius composition (R4 post-mortem: saturated
// params make the map locally expansive (f' ~ 5e5); the per-step clip is a
// material nonlinearity there -> associative composition is wrong, not just
// imprecise).

typedef unsigned int uint;
typedef unsigned short ushort_t;
typedef __attribute__((ext_vector_type(8))) short short8;
typedef __attribute__((ext_vector_type(4))) float f32x4;

#define SS 1000
#define HH 512
#define TT 200
#define BB_ 65536
#define PP 5

#define OFF_EMB   0
#define OFF_B1    512000
#define OFF_B2    512512
#define OFF_WOUT  513024
#define OFF_BOUT  515584
#define CONV_TOT  515589

__device__ __forceinline__ float b2f(ushort_t u) {
    return __uint_as_float(((uint)u) << 16);
}
__device__ __forceinline__ ushort_t f2b(float f) {
    uint u = __float_as_uint(f);
    uint r = u + 0x7FFFu + ((u >> 16) & 1u);   // RNE
    return (ushort_t)(r >> 16);
}
// Per-wave dtype detect (R2/R3: dataset is f32; keep both paths).
__device__ __forceinline__ int detect_bf16(const uint* __restrict__ embed_raw,
                                           int tid) {
    uint w = embed_raw[tid & 63];
    uint e = (w >> 7) & 0xFFu;
    bool pl = (e >= 117u && e <= 130u);
    return __popcll(__ballot(pl)) >= 32 ? 1 : 0;
}
__device__ __forceinline__ ushort_t ld_bf16(const void* src, int idx, int fb) {
    return fb ? ((const ushort_t*)src)[idx] : f2b(((const float*)src)[idx]);
}

// The one true step. Used identically (same fp ops, same order) in scan_a
// and scan_b so checkpoint-resumed trajectories are bit-exact.
__device__ __forceinline__ float bkt_step(float latent, bool yt,
                                          float oms, float omg, float A1,
                                          float A0, float g, float s,
                                          float oml, float l,
                                          float* correct_out) {
    float num1    = latent * oms;
    float correct = fmaf(latent, A1, g);
    float lats    = latent * s;
    float num = yt ? num1 : lats;
    float den = yt ? correct : fmaf(latent, A0, omg);
    float kt  = num * __builtin_amdgcn_rcpf(den);
    *correct_out = correct;
    float nxt = fmaf(kt, oml, l);
    return fminf(fmaxf(nxt, 1e-6f), 1.f - 1e-6f);
}

// ------------------------------------------------------------------- prep
__global__ __launch_bounds__(256) void prep_kernel(
    const void* __restrict__ embed, const void* __restrict__ W1,
    const void* __restrict__ b1,    const void* __restrict__ W2,
    const void* __restrict__ b2,    const void* __restrict__ Wout,
    const void* __restrict__ bout,
    ushort_t* __restrict__ conv, ushort_t* __restrict__ WT1,
    ushort_t* __restrict__ WT2)
{
    int tid = threadIdx.x;
    int fb = detect_bf16((const uint*)embed, tid);
    int bx = blockIdx.x;
    if (bx < 2015) {
        int i = bx * 256 + tid;
        if (i < CONV_TOT) {
            const void* src; int off;
            if      (i < OFF_B1)   { src = embed; off = i; }
            else if (i < OFF_B2)   { src = b1;    off = i - OFF_B1; }
            else if (i < OFF_WOUT) { src = b2;    off = i - OFF_B2; }
            else if (i < OFF_BOUT) { src = Wout;  off = i - OFF_WOUT; }
            else                   { src = bout;  off = i - OFF_BOUT; }
            conv[i] = ld_bf16(src, off, fb);
        }
    } else {
        __shared__ ushort_t t[32][33];
        int bi = bx - 2015;
        const void* W = bi < 256 ? W1 : W2;
        ushort_t* WT = bi < 256 ? WT1 : WT2;
        int ti = bi & 255;
        int k0 = (ti & 15) * 32, n0 = (ti >> 4) * 32;
        int tx = tid & 31, ty = tid >> 5;
        #pragma unroll
        for (int i = ty; i < 32; i += 8)
            t[i][tx] = ld_bf16(W, (k0 + i) * HH + n0 + tx, fb);
        __syncthreads();
        #pragma unroll
        for (int i = ty; i < 32; i += 8)
            WT[(n0 + i) * HH + k0 + tx] = t[tx][i];
    }
}

// -------------------------------------------------------------- MLP layer
// Wave computes 16x16 tile; grid (16,32)=512 blocks (2 blocks/CU).
__global__ __launch_bounds__(256) void mlp_layer(
    const ushort_t* __restrict__ A, const ushort_t* __restrict__ WT,
    const ushort_t* __restrict__ bias, ushort_t* __restrict__ H, int Mclamp)
{
    int tid = threadIdx.x;
    int lane = tid & 63;
    int wave = tid >> 6;
    int m_base = blockIdx.x * 64 + wave * 16;
    int n_base = blockIdx.y * 16;
    int lrow = lane & 15;
    int q = lane >> 4;
    int rowA = m_base + lrow; if (rowA > Mclamp) rowA = Mclamp;

    const short8* Ap = (const short8*)(A + (size_t)rowA * HH) + q;
    const short8* Bp = (const short8*)(WT + (size_t)(n_base + lrow) * HH) + q;

    f32x4 acc = {0.f, 0.f, 0.f, 0.f};
    #pragma unroll 8
    for (int kk = 0; kk < 16; kk++) {
        short8 a = Ap[kk * 4];
        short8 b = Bp[kk * 4];
        acc = __builtin_amdgcn_mfma_f32_16x16x32_bf16(a, b, acc, 0, 0, 0);
    }

    int orow = m_base + q * 4;                 // C/D: col=lane&15, row=q*4+reg
    int n = n_base + lrow;
    float bb = b2f(bias[n]);
    #pragma unroll
    for (int r = 0; r < 4; r++) {
        float v = acc[r] + bb;
        H[(size_t)(orow + r) * HH + n] = f2b(fmaxf(v, 0.f));
    }
}

// ---------------------------------------------------------------- params
__global__ __launch_bounds__(256) void params_kernel(
    const ushort_t* __restrict__ h2, const ushort_t* __restrict__ conv,
    float* __restrict__ table)
{
    int wid = blockIdx.x * 4 + (threadIdx.x >> 6);
    int lane = threadIdx.x & 63;
    if (wid >= SS * PP) return;
    int row = wid / PP, p = wid - row * PP;
    const ushort_t* Wout = conv + OFF_WOUT;
    const ushort_t* bout = conv + OFF_BOUT;
    const short8* hr = (const short8*)(h2 + (size_t)row * HH);
    short8 h = hr[lane];
    float acc = 0.f;
    #pragma unroll
    for (int j = 0; j < 8; j++) {
        int k = lane * 8 + j;
        acc += b2f((ushort_t)h[j]) * b2f(Wout[k * PP + p]);
    }
    #pragma unroll
    for (int m = 32; m; m >>= 1) acc += __shfl_xor(acc, m);
    if (lane == 0) {
        float x = acc + b2f(bout[p]);
        float sg = 1.f / (1.f + expf(-x));
        sg = fminf(fmaxf(sg, 1e-6f), 1.f - 1e-6f);
        table[(size_t)row * 8 + p] = sg;
    }
}

// ----------------------------------------------------------------- scan_a
// 1 thread/row: read y once, pack 8x25-bit masks, run exact recurrence
// latent-only, write checkpoints+masks planar ([w][B] -> coalesced).
__global__ __launch_bounds__(256) void scan_a(
    const int* __restrict__ X, const int* __restrict__ y,
    const float* __restrict__ table,
    float* __restrict__ cpA, uint* __restrict__ maskA)
{
    int r = blockIdx.x * 256 + threadIdx.x;
    const int4* yrow = (const int4*)(y + (size_t)r * TT);
    uint u[8] = {0, 0, 0, 0, 0, 0, 0, 0};
    #pragma unroll
    for (int k = 0; k < 50; k++) {
        int4 v = yrow[k];
        int t = 4 * k;
        u[(t + 0) / 25] |= (uint)(v.x == 1) << ((t + 0) % 25);
        u[(t + 1) / 25] |= (uint)(v.y == 1) << ((t + 1) % 25);
        u[(t + 2) / 25] |= (uint)(v.z == 1) << ((t + 2) % 25);
        u[(t + 3) / 25] |= (uint)(v.w == 1) << ((t + 3) % 25);
    }

    int xi = X[r]; xi = xi < 0 ? 0 : (xi >= SS ? SS - 1 : xi);
    float l      = table[xi * 8 + 0];
    float g      = table[xi * 8 + 2];
    float s      = table[xi * 8 + 3];
    float latent = table[xi * 8 + 4];
    float oms = 1.f - s, omg = 1.f - g, oml = 1.f - l;
    float A1 = 1.f - s - g, A0 = s + g - 1.f;

    float cp[8];
    #pragma unroll
    for (int w = 0; w < 8; w++) {
        cp[w] = latent;
        uint uw = u[w];
        #pragma unroll
        for (int i = 0; i < 25; i++) {
            float cdummy;
            latent = bkt_step(latent, (uw >> i) & 1u,
                              oms, omg, A1, A0, g, s, oml, l, &cdummy);
        }
    }
    #pragma unroll
    for (int w = 0; w < 8; w++) {
        cpA[(size_t)w * BB_ + r]   = cp[w];
        maskA[(size_t)w * BB_ + r] = u[w];
    }
}

// ----------------------------------------------------------------- scan_b
// 8 threads/row (8192 waves, full occupancy): resume from checkpoint,
// re-emit 25 steps bit-identically, store outputs.
__global__ __launch_bounds__(256) void scan_b(
    const int* __restrict__ X, const float* __restrict__ table,
    const float* __restrict__ cpA, const uint* __restrict__ maskA,
    const uint* __restrict__ embed_raw, void* __restrict__ out)
{
    int tid = blockIdx.x * 256 + threadIdx.x;
    int r = tid >> 3;
    int j = tid & 7;
    int fb = detect_bf16(embed_raw, threadIdx.x);

    int xi = X[r]; xi = xi < 0 ? 0 : (xi >= SS ? SS - 1 : xi);
    float l  = table[xi * 8 + 0];
    float p1 = table[xi * 8 + 1];
    float g  = table[xi * 8 + 2];
    float s  = table[xi * 8 + 3];
    float L0 = table[xi * 8 + 4];

    if (j < 5) {
        float pv = j == 0 ? l : j == 1 ? p1 : j == 2 ? g : j == 3 ? s : L0;
        size_t po = 2ull * BB_ * TT + (size_t)r * 5 + j;
        if (fb) ((ushort_t*)out)[po] = f2b(pv);
        else    ((float*)out)[po] = pv;
    }

    float latent = cpA[(size_t)j * BB_ + r];
    uint  u      = maskA[(size_t)j * BB_ + r];
    float oms = 1.f - s, omg = 1.f - g, oml = 1.f - l;
    float A1 = 1.f - s - g, A0 = s + g - 1.f;

    char* cgb = (char*)out;
    char* lgb = (char*)out + (fb ? 2ull : 4ull) * BB_ * TT;
    size_t eoff = (size_t)r * TT + j * 25;
    #pragma unroll
    for (int i = 0; i < 25; i++) {
        float correct;
        float nxt = bkt_step(latent, (u >> i) & 1u,
                             oms, omg, A1, A0, g, s, oml, l, &correct);
        if (fb) {
            ((ushort_t*)cgb)[eoff + i] = f2b(correct);
            ((ushort_t*)lgb)[eoff + i] = f2b(latent);
        } else {
            ((float*)cgb)[eoff + i] = correct;
            ((float*)lgb)[eoff + i] = latent;
        }
        latent = nxt;
    }
}

// ---------------------------------------------------------------- launch
extern "C" void kernel_launch(void* const* d_in, const int* in_sizes, int n_in,
                              void* d_out, int out_size, void* d_ws, size_t ws_size,
                              hipStream_t stream) {
    const int* X = (const int*)d_in[0];
    const int* y = (const int*)d_in[1];

    char* ws = (char*)d_ws;
    ushort_t* conv  = (ushort_t*)(ws);
    ushort_t* WT1   = (ushort_t*)(ws + 1048576);
    ushort_t* WT2   = (ushort_t*)(ws + 1572864);
    ushort_t* h1    = (ushort_t*)(ws + 2097152);
    ushort_t* h2    = (ushort_t*)(ws + 3145728);
    float*    table = (float*)(ws + 4194304);          // 32 KB
    float*    cpA   = (float*)(ws + 4227072);          // 8*65536*4 = 2 MB
    uint*     maskA = (uint*)(ws + 6324224);           // 2 MB

    prep_kernel<<<dim3(2527, 1, 1), 256, 0, stream>>>(
        d_in[2], d_in[3], d_in[4], d_in[5], d_in[6], d_in[7], d_in[8],
        conv, WT1, WT2);
    mlp_layer<<<dim3(16, 32, 1), 256, 0, stream>>>(conv + OFF_EMB, WT1, conv + OFF_B1, h1, SS - 1);
    mlp_layer<<<dim3(16, 32, 1), 256, 0, stream>>>(h1, WT2, conv + OFF_B2, h2, 1023);
    params_kernel<<<dim3(1250, 1, 1), 256, 0, stream>>>(h2, conv, table);
    scan_a<<<dim3(BB_ / 256, 1, 1), 256, 0, stream>>>(X, y, table, cpA, maskA);
    scan_b<<<dim3((BB_ * 8) / 256, 1, 1), 256, 0, stream>>>(
        X, table, cpA, maskA, (const uint*)d_in[2], (void*)d_out);
}

// Round 6
// 208.943 us; speedup vs baseline: 1.6593x; 1.6593x over previous
//
#include <hip/hip_runtime.h>

// MLP depends only on X[b] (1000 distinct values) -> params table once over
// embedding rows, gather in the scan. Scan = EXACT two-pass checkpoint
// scheme: scan_a (1 thread/row) runs the clipped recurrence latent-only and
// stores 8 checkpoint latents + 8x25-bit y masks per row; scan_b (8
// threads/row, full occupancy) re-emits each 25-step segment bit-identically.
// R5 lesson: scan_b's per-lane strided stores caused 4.85x HBM write
// amplification (514 MB vs 106 MB ideal) -> this round stages the 32x200
// output tile in LDS and stores it as one contiguous uint4 stream per block.

typedef unsigned int uint;
typedef unsigned short ushort_t;
typedef __attribute__((ext_vector_type(8))) short short8;
typedef __attribute__((ext_vector_type(4))) float f32x4;

#define SS 1000
#define HH 512
#define TT 200
#define BB_ 65536
#define PP 5

#define OFF_EMB   0
#define OFF_B1    512000
#define OFF_B2    512512
#define OFF_WOUT  513024
#define OFF_BOUT  515584
#define CONV_TOT  515589

__device__ __forceinline__ float b2f(ushort_t u) {
    return __uint_as_float(((uint)u) << 16);
}
__device__ __forceinline__ ushort_t f2b(float f) {
    uint u = __float_as_uint(f);
    uint r = u + 0x7FFFu + ((u >> 16) & 1u);   // RNE
    return (ushort_t)(r >> 16);
}
// Per-wave dtype detect (R2-R5: dataset is f32; keep both paths).
__device__ __forceinline__ int detect_bf16(const uint* __restrict__ embed_raw,
                                           int tid) {
    uint w = embed_raw[tid & 63];
    uint e = (w >> 7) & 0xFFu;
    bool pl = (e >= 117u && e <= 130u);
    return __popcll(__ballot(pl)) >= 32 ? 1 : 0;
}
__device__ __forceinline__ ushort_t ld_bf16(const void* src, int idx, int fb) {
    return fb ? ((const ushort_t*)src)[idx] : f2b(((const float*)src)[idx]);
}

// The one true step. Identical fp ops/order in scan_a and scan_b so
// checkpoint-resumed trajectories are bit-exact.
__device__ __forceinline__ float bkt_step(float latent, bool yt,
                                          float oms, float omg, float A1,
                                          float A0, float g, float s,
                                          float oml, float l,
                                          float* correct_out) {
    float num1    = latent * oms;
    float correct = fmaf(latent, A1, g);
    float lats    = latent * s;
    float num = yt ? num1 : lats;
    float den = yt ? correct : fmaf(latent, A0, omg);
    float kt  = num * __builtin_amdgcn_rcpf(den);
    *correct_out = correct;
    float nxt = fmaf(kt, oml, l);
    return fminf(fmaxf(nxt, 1e-6f), 1.f - 1e-6f);
}

// ------------------------------------------------------------------- prep
__global__ __launch_bounds__(256) void prep_kernel(
    const void* __restrict__ embed, const void* __restrict__ W1,
    const void* __restrict__ b1,    const void* __restrict__ W2,
    const void* __restrict__ b2,    const void* __restrict__ Wout,
    const void* __restrict__ bout,
    ushort_t* __restrict__ conv, ushort_t* __restrict__ WT1,
    ushort_t* __restrict__ WT2)
{
    int tid = threadIdx.x;
    int fb = detect_bf16((const uint*)embed, tid);
    int bx = blockIdx.x;
    if (bx < 2015) {
        int i = bx * 256 + tid;
        if (i < CONV_TOT) {
            const void* src; int off;
            if      (i < OFF_B1)   { src = embed; off = i; }
            else if (i < OFF_B2)   { src = b1;    off = i - OFF_B1; }
            else if (i < OFF_WOUT) { src = b2;    off = i - OFF_B2; }
            else if (i < OFF_BOUT) { src = Wout;  off = i - OFF_WOUT; }
            else                   { src = bout;  off = i - OFF_BOUT; }
            conv[i] = ld_bf16(src, off, fb);
        }
    } else {
        __shared__ ushort_t t[32][33];
        int bi = bx - 2015;
        const void* W = bi < 256 ? W1 : W2;
        ushort_t* WT = bi < 256 ? WT1 : WT2;
        int ti = bi & 255;
        int k0 = (ti & 15) * 32, n0 = (ti >> 4) * 32;
        int tx = tid & 31, ty = tid >> 5;
        #pragma unroll
        for (int i = ty; i < 32; i += 8)
            t[i][tx] = ld_bf16(W, (k0 + i) * HH + n0 + tx, fb);
        __syncthreads();
        #pragma unroll
        for (int i = ty; i < 32; i += 8)
            WT[(n0 + i) * HH + k0 + tx] = t[tx][i];
    }
}

// -------------------------------------------------------------- MLP layer
__global__ __launch_bounds__(256) void mlp_layer(
    const ushort_t* __restrict__ A, const ushort_t* __restrict__ WT,
    const ushort_t* __restrict__ bias, ushort_t* __restrict__ H, int Mclamp)
{
    int tid = threadIdx.x;
    int lane = tid & 63;
    int wave = tid >> 6;
    int m_base = blockIdx.x * 64 + wave * 16;
    int n_base = blockIdx.y * 16;
    int lrow = lane & 15;
    int q = lane >> 4;
    int rowA = m_base + lrow; if (rowA > Mclamp) rowA = Mclamp;

    const short8* Ap = (const short8*)(A + (size_t)rowA * HH) + q;
    const short8* Bp = (const short8*)(WT + (size_t)(n_base + lrow) * HH) + q;

    f32x4 acc = {0.f, 0.f, 0.f, 0.f};
    #pragma unroll 8
    for (int kk = 0; kk < 16; kk++) {
        short8 a = Ap[kk * 4];
        short8 b = Bp[kk * 4];
        acc = __builtin_amdgcn_mfma_f32_16x16x32_bf16(a, b, acc, 0, 0, 0);
    }

    int orow = m_base + q * 4;                 // C/D: col=lane&15, row=q*4+reg
    int n = n_base + lrow;
    float bb = b2f(bias[n]);
    #pragma unroll
    for (int r = 0; r < 4; r++) {
        float v = acc[r] + bb;
        H[(size_t)(orow + r) * HH + n] = f2b(fmaxf(v, 0.f));
    }
}

// ---------------------------------------------------------------- params
__global__ __launch_bounds__(256) void params_kernel(
    const ushort_t* __restrict__ h2, const ushort_t* __restrict__ conv,
    float* __restrict__ table)
{
    int wid = blockIdx.x * 4 + (threadIdx.x >> 6);
    int lane = threadIdx.x & 63;
    if (wid >= SS * PP) return;
    int row = wid / PP, p = wid - row * PP;
    const ushort_t* Wout = conv + OFF_WOUT;
    const ushort_t* bout = conv + OFF_BOUT;
    const short8* hr = (const short8*)(h2 + (size_t)row * HH);
    short8 h = hr[lane];
    float acc = 0.f;
    #pragma unroll
    for (int j = 0; j < 8; j++) {
        int k = lane * 8 + j;
        acc += b2f((ushort_t)h[j]) * b2f(Wout[k * PP + p]);
    }
    #pragma unroll
    for (int m = 32; m; m >>= 1) acc += __shfl_xor(acc, m);
    if (lane == 0) {
        float x = acc + b2f(bout[p]);
        float sg = 1.f / (1.f + expf(-x));
        sg = fminf(fmaxf(sg, 1e-6f), 1.f - 1e-6f);
        table[(size_t)row * 8 + p] = sg;
    }
}

// ----------------------------------------------------------------- scan_a
// 1 thread/row: read y once, pack 8x25-bit masks, run exact recurrence
// latent-only, write checkpoints+masks planar ([w][B] -> coalesced).
__global__ __launch_bounds__(256) void scan_a(
    const int* __restrict__ X, const int* __restrict__ y,
    const float* __restrict__ table,
    float* __restrict__ cpA, uint* __restrict__ maskA)
{
    int r = blockIdx.x * 256 + threadIdx.x;
    const int4* yrow = (const int4*)(y + (size_t)r * TT);
    uint u[8] = {0, 0, 0, 0, 0, 0, 0, 0};
    #pragma unroll
    for (int k = 0; k < 50; k++) {
        int4 v = yrow[k];
        int t = 4 * k;
        u[(t + 0) / 25] |= (uint)(v.x == 1) << ((t + 0) % 25);
        u[(t + 1) / 25] |= (uint)(v.y == 1) << ((t + 1) % 25);
        u[(t + 2) / 25] |= (uint)(v.z == 1) << ((t + 2) % 25);
        u[(t + 3) / 25] |= (uint)(v.w == 1) << ((t + 3) % 25);
    }

    int xi = X[r]; xi = xi < 0 ? 0 : (xi >= SS ? SS - 1 : xi);
    float l      = table[xi * 8 + 0];
    float g      = table[xi * 8 + 2];
    float s      = table[xi * 8 + 3];
    float latent = table[xi * 8 + 4];
    float oms = 1.f - s, omg = 1.f - g, oml = 1.f - l;
    float A1 = 1.f - s - g, A0 = s + g - 1.f;

    float cp[8];
    #pragma unroll
    for (int w = 0; w < 8; w++) {
        cp[w] = latent;
        uint uw = u[w];
        #pragma unroll
        for (int i = 0; i < 25; i++) {
            float cdummy;
            latent = bkt_step(latent, (uw >> i) & 1u,
                              oms, omg, A1, A0, g, s, oml, l, &cdummy);
        }
    }
    #pragma unroll
    for (int w = 0; w < 8; w++) {
        cpA[(size_t)w * BB_ + r]   = cp[w];
        maskA[(size_t)w * BB_ + r] = u[w];
    }
}

// ----------------------------------------------------------------- scan_b
// 8 threads/row, block = 32 rows. Emit correct -> LDS tile (addr 25*lane+i:
// 2-way bank alias = free), latents kept in regs; then contiguous uint4
// block stores (32x200 f32 = 25.6 KB per array, perfectly coalesced).
__global__ __launch_bounds__(256) void scan_b(
    const int* __restrict__ X, const float* __restrict__ table,
    const float* __restrict__ cpA, const uint* __restrict__ maskA,
    const uint* __restrict__ embed_raw, void* __restrict__ out)
{
    __shared__ __align__(16) float stg[32 * 200];
    int tid = blockIdx.x * 256 + threadIdx.x;
    int r = tid >> 3;
    int j = tid & 7;
    int lr = threadIdx.x >> 3;                 // local row 0..31
    int rbase = blockIdx.x * 32;
    int fb = detect_bf16(embed_raw, threadIdx.x);

    int xi = X[r]; xi = xi < 0 ? 0 : (xi >= SS ? SS - 1 : xi);
    float l  = table[xi * 8 + 0];
    float p1 = table[xi * 8 + 1];
    float g  = table[xi * 8 + 2];
    float s  = table[xi * 8 + 3];
    float L0 = table[xi * 8 + 4];

    if (j < 5) {
        float pv = j == 0 ? l : j == 1 ? p1 : j == 2 ? g : j == 3 ? s : L0;
        size_t po = 2ull * BB_ * TT + (size_t)r * 5 + j;
        if (fb) ((ushort_t*)out)[po] = f2b(pv);
        else    ((float*)out)[po] = pv;
    }

    float latent = cpA[(size_t)j * BB_ + r];
    uint  u      = maskA[(size_t)j * BB_ + r];
    float oms = 1.f - s, omg = 1.f - g, oml = 1.f - l;
    float A1 = 1.f - s - g, A0 = s + g - 1.f;

    if (fb) {
        // bf16 path (unused on this dataset): simple scalar stores.
        ushort_t* cgb = (ushort_t*)out;
        ushort_t* lgb = (ushort_t*)out + (size_t)BB_ * TT;
        size_t eoff = (size_t)r * TT + j * 25;
        #pragma unroll
        for (int i = 0; i < 25; i++) {
            float correct;
            float nxt = bkt_step(latent, (u >> i) & 1u,
                                 oms, omg, A1, A0, g, s, oml, l, &correct);
            cgb[eoff + i] = f2b(correct);
            lgb[eoff + i] = f2b(latent);
            latent = nxt;
        }
        return;
    }

    // f32 path: correct -> LDS, latent -> regs
    float lat_arr[25];
    int sbase = lr * 200 + j * 25;
    #pragma unroll
    for (int i = 0; i < 25; i++) {
        float correct;
        float nxt = bkt_step(latent, (u >> i) & 1u,
                             oms, omg, A1, A0, g, s, oml, l, &correct);
        stg[sbase + i] = correct;
        lat_arr[i] = latent;
        latent = nxt;
    }
    __syncthreads();
    // contiguous block store of corrects: 1600 uint4
    {
        const uint4* src = (const uint4*)stg;
        uint4* dst = (uint4*)((float*)out + (size_t)rbase * TT);
        for (int idx = threadIdx.x; idx < 1600; idx += 256)
            dst[idx] = src[idx];
    }
    __syncthreads();
    #pragma unroll
    for (int i = 0; i < 25; i++)
        stg[sbase + i] = lat_arr[i];
    __syncthreads();
    {
        const uint4* src = (const uint4*)stg;
        uint4* dst = (uint4*)((float*)out + (size_t)BB_ * TT + (size_t)rbase * TT);
        for (int idx = threadIdx.x; idx < 1600; idx += 256)
            dst[idx] = src[idx];
    }
}

// ---------------------------------------------------------------- launch
extern "C" void kernel_launch(void* const* d_in, const int* in_sizes, int n_in,
                              void* d_out, int out_size, void* d_ws, size_t ws_size,
                              hipStream_t stream) {
    const int* X = (const int*)d_in[0];
    const int* y = (const int*)d_in[1];

    char* ws = (char*)d_ws;
    ushort_t* conv  = (ushort_t*)(ws);
    ushort_t* WT1   = (ushort_t*)(ws + 1048576);
    ushort_t* WT2   = (ushort_t*)(ws + 1572864);
    ushort_t* h1    = (ushort_t*)(ws + 2097152);
    ushort_t* h2    = (ushort_t*)(ws + 3145728);
    float*    table = (float*)(ws + 4194304);          // 32 KB
    float*    cpA   = (float*)(ws + 4227072);          // 2 MB
    uint*     maskA = (uint*)(ws + 6324224);           // 2 MB

    prep_kernel<<<dim3(2527, 1, 1), 256, 0, stream>>>(
        d_in[2], d_in[3], d_in[4], d_in[5], d_in[6], d_in[7], d_in[8],
        conv, WT1, WT2);
    mlp_layer<<<dim3(16, 32, 1), 256, 0, stream>>>(conv + OFF_EMB, WT1, conv + OFF_B1, h1, SS - 1);
    mlp_layer<<<dim3(16, 32, 1), 256, 0, stream>>>(h1, WT2, conv + OFF_B2, h2, 1023);
    params_kernel<<<dim3(1250, 1, 1), 256, 0, stream>>>(h2, conv, table);
    scan_a<<<dim3(BB_ / 256, 1, 1), 256, 0, stream>>>(X, y, table, cpA, maskA);
    scan_b<<<dim3((BB_ * 8) / 256, 1, 1), 256, 0, stream>>>(
        X, table, cpA, maskA, (const uint*)d_in[2], (void*)d_out);
}